// Round 10
// baseline (289.519 us; speedup 1.0000x reference)
//
#include <hip/hip_runtime.h>
#include <hip/hip_bf16.h>
#include <math.h>

// f32 harness I/O; bf16 MFMA internally with fp32 accumulate.
typedef __bf16 bf16_t;
typedef bf16_t bf16x4 __attribute__((ext_vector_type(4)));
typedef bf16_t bf16x8 __attribute__((ext_vector_type(8)));
typedef float f32x4 __attribute__((ext_vector_type(4)));

#define MFMA16(a, b, c) __builtin_amdgcn_mfma_f32_16x16x32_bf16(a, b, c, 0, 0, 0)
// Async global->LDS, 16B/lane. LDS dest must be wave-uniform base + lane*16.
#define GLDS16(g, s)                                                       \
  __builtin_amdgcn_global_load_lds(                                        \
      (const __attribute__((address_space(1))) void*)(g),                  \
      (__attribute__((address_space(3))) void*)(s), 16, 0, 0)

constexpr int E_DIM = 1024;
constexpr int T_SEQ = 2048;
constexpr int BATCH = 4;
constexpr int NH = 16;
constexpr int HD = 64;
constexpr int M_TOT = BATCH * T_SEQ;  // 8192
constexpr size_t ME = (size_t)M_TOT * E_DIM;  // 2^23
constexpr size_t EE = (size_t)E_DIM * E_DIM;  // 2^20

// One conversion launch: flat elems [0,ME) -> x, then 4 weight matrices.
__global__ __launch_bounds__(256) void cvt_all(
    const float* __restrict__ x, const float* __restrict__ w0,
    const float* __restrict__ w1, const float* __restrict__ w2,
    const float* __restrict__ w3, bf16_t* __restrict__ xb,
    bf16_t* __restrict__ dcat, bf16_t* __restrict__ d3) {
  size_t i = (size_t)(blockIdx.x * blockDim.x + threadIdx.x) * 8;
  const float* s;
  bf16_t* d;
  if (i < ME) {
    s = x + i;
    d = xb + i;
  } else {
    size_t rem = i - ME;
    int wsel = (int)(rem >> 20);
    size_t off = rem & (EE - 1);
    s = ((wsel == 0) ? w0 : (wsel == 1) ? w1 : (wsel == 2) ? w2 : w3) + off;
    d = ((wsel < 3) ? (dcat + (size_t)wsel * EE) : d3) + off;
  }
  float4 a = *(const float4*)s;
  float4 b = *(const float4*)(s + 4);
  bf16x8 o;
  o[0] = (bf16_t)a.x; o[1] = (bf16_t)a.y; o[2] = (bf16_t)a.z; o[3] = (bf16_t)a.w;
  o[4] = (bf16_t)b.x; o[5] = (bf16_t)b.y; o[6] = (bf16_t)b.z; o[7] = (bf16_t)b.w;
  *(bf16x8*)d = o;
}

// Fused QKV projection, 128x128 tile (m97 config), 1536 blocks, 2D XCD
// swizzle (see R7). sel = n0>>10 block-uniform: 0->Q [B,H,T,D],
// 1->K [B,H,T,D], 2->V^T [B,H,D,T] with keys stored in SLOT-PERMUTED
// order within each 64-key group: t = 32u+16b+4q+m -> 32u+8q+4b+m, the
// exact MFMA k-slot order attn's PV consumes — attn V staging becomes a
// pure b128 copy (no repack).
__global__ __launch_bounds__(256) void gemm_qkv(
    const bf16_t* __restrict__ A, const bf16_t* __restrict__ Wcat,
    const float* __restrict__ biq, const float* __restrict__ bik,
    const float* __restrict__ biv, bf16_t* __restrict__ QKV, float qscale) {
  __shared__ __align__(16) bf16_t As[128][32];
  __shared__ __align__(16) bf16_t Bs[128][32];
  const int tid = threadIdx.x;
  const int lane = tid & 63;
  const int w = tid >> 6;
  const int quad = lane >> 4;
  const int l16 = lane & 15;
  const int wr = w >> 1, wc = w & 1;  // 2x2 wave grid, 64x64 per wave

  // Swizzle: bid -> (mb in [0,64), nb in [0,24))
  const int bid = blockIdx.x;
  const int x8 = bid & 7;
  const int s = bid >> 3;          // [0,192)
  const int nb = (x8 >> 1) * 6 + (s % 6);
  const int mb = (x8 & 1) * 32 + (s / 6);
  const int m0 = mb * 128;
  const int n0 = nb * 128;
  constexpr int K = E_DIM;

  const int srow = tid >> 2;
  const int scol = (tid & 3) * 8;
  const bf16_t* gA = A + (size_t)(m0 + srow) * K + scol;
  const bf16_t* gB = Wcat + (size_t)(n0 + srow) * K + scol;
  bf16_t* sA = &As[0][0] + tid * 8;
  bf16_t* sB = &Bs[0][0] + tid * 8;

  f32x4 acc[4][4];
#pragma unroll
  for (int i = 0; i < 4; i++)
#pragma unroll
    for (int j = 0; j < 4; j++) acc[i][j] = f32x4{0.f, 0.f, 0.f, 0.f};

  for (int k0 = 0; k0 < K; k0 += 32) {
    GLDS16(gA + k0, sA);
    GLDS16(gA + k0 + (size_t)64 * K, sA + 2048);
    GLDS16(gB + k0, sB);
    GLDS16(gB + k0 + (size_t)64 * K, sB + 2048);
    __syncthreads();
    bf16x8 af[4], bfr[4];
#pragma unroll
    for (int i = 0; i < 4; i++)
      af[i] = *(const bf16x8*)&As[wr * 64 + i * 16 + l16][quad * 8];
#pragma unroll
    for (int j = 0; j < 4; j++)
      bfr[j] = *(const bf16x8*)&Bs[wc * 64 + j * 16 + l16][quad * 8];
#pragma unroll
    for (int i = 0; i < 4; i++)
#pragma unroll
      for (int j = 0; j < 4; j++) acc[i][j] = MFMA16(af[i], bfr[j], acc[i][j]);
    __syncthreads();
  }

  // Epilogue: block-uniform matrix select; C/D layout col=l16, row=quad*4+r.
  const int sel = n0 >> 10;
  const float* bp = (sel == 0) ? biq : (sel == 1) ? bik : biv;
  const float scale = (sel == 0) ? qscale : 1.0f;
  bf16_t* outb = QKV + (size_t)sel * ME;
#pragma unroll
  for (int j = 0; j < 4; j++) {
    int col = n0 + wc * 64 + j * 16 + l16;
    int coln = col & 1023;
    int h = coln >> 6, d = coln & 63;
    float bvl = bp[coln];
#pragma unroll
    for (int i = 0; i < 4; i++) {
      if (sel == 2) {
        // V^T [B,H,D,T], slot-permuted keys. rows quad*4+r span m=0..3 of
        // t6 = 32u+16b+4q+m -> pi(t6) = 32u+8q+4b+m; contiguous bf16x4.
        int row0 = m0 + wr * 64 + i * 16 + quad * 4;
        int bb = row0 >> 11, t = row0 & (T_SEQ - 1);
        int t6 = t & 63;
        int tp = (t & ~63) | (t6 & 32) | ((t6 & 12) << 1) |
                 (((t6 >> 4) & 1) << 2) | (t6 & 3);
        bf16x4 ov;
#pragma unroll
        for (int r = 0; r < 4; r++) ov[r] = (bf16_t)(acc[i][j][r] + bvl);
        *(bf16x4*)(outb + ((size_t)(bb * NH + h) * HD + d) * T_SEQ + tp) = ov;
      } else {
#pragma unroll
        for (int r = 0; r < 4; r++) {
          int row = m0 + wr * 64 + i * 16 + quad * 4 + r;
          int bb = row >> 11, t = row & (T_SEQ - 1);
          float v = (acc[i][j][r] + bvl) * scale;
          outb[((size_t)(bb * NH + h) * T_SEQ + t) * HD + d] = (bf16_t)v;
        }
      }
    }
  }
}

// Output projection, 128x128 tile, 512 blocks, same 2D XCD swizzle: f32 out.
__global__ __launch_bounds__(256) void gemm_o(const bf16_t* __restrict__ A,
                                              const bf16_t* __restrict__ W,
                                              const float* __restrict__ bias,
                                              float* __restrict__ outf) {
  constexpr int N = E_DIM, K = E_DIM;
  __shared__ __align__(16) bf16_t As[128][32];
  __shared__ __align__(16) bf16_t Bs[128][32];
  const int tid = threadIdx.x;
  const int lane = tid & 63;
  const int w = tid >> 6;
  const int quad = lane >> 4;
  const int l16 = lane & 15;
  const int wr = w >> 1, wc = w & 1;

  const int bid = blockIdx.x;  // [0,512)
  const int x8 = bid & 7;
  const int s = bid >> 3;  // [0,64)
  const int nb = (x8 >> 1) * 2 + (s & 1);
  const int mb = (x8 & 1) * 32 + (s >> 1);
  const int m0 = mb * 128;
  const int n0 = nb * 128;

  const int srow = tid >> 2;
  const int scol = (tid & 3) * 8;
  const bf16_t* gA = A + (size_t)(m0 + srow) * K + scol;
  const bf16_t* gB = W + (size_t)(n0 + srow) * K + scol;
  bf16_t* sA = &As[0][0] + tid * 8;
  bf16_t* sB = &Bs[0][0] + tid * 8;

  f32x4 acc[4][4];
#pragma unroll
  for (int i = 0; i < 4; i++)
#pragma unroll
    for (int j = 0; j < 4; j++) acc[i][j] = f32x4{0.f, 0.f, 0.f, 0.f};

  for (int k0 = 0; k0 < K; k0 += 32) {
    GLDS16(gA + k0, sA);
    GLDS16(gA + k0 + (size_t)64 * K, sA + 2048);
    GLDS16(gB + k0, sB);
    GLDS16(gB + k0 + (size_t)64 * K, sB + 2048);
    __syncthreads();
    bf16x8 af[4], bfr[4];
#pragma unroll
    for (int i = 0; i < 4; i++)
      af[i] = *(const bf16x8*)&As[wr * 64 + i * 16 + l16][quad * 8];
#pragma unroll
    for (int j = 0; j < 4; j++)
      bfr[j] = *(const bf16x8*)&Bs[wc * 64 + j * 16 + l16][quad * 8];
#pragma unroll
    for (int i = 0; i < 4; i++)
#pragma unroll
      for (int j = 0; j < 4; j++) acc[i][j] = MFMA16(af[i], bfr[j], acc[i][j]);
    __syncthreads();
  }

#pragma unroll
  for (int j = 0; j < 4; j++) {
    int col = n0 + wc * 64 + j * 16 + l16;
    float bv = bias[col];
#pragma unroll
    for (int i = 0; i < 4; i++) {
#pragma unroll
      for (int r = 0; r < 4; r++) {
        int row = m0 + wr * 64 + i * 16 + quad * 4 + r;
        outf[(size_t)row * N + col] = acc[i][j][r] + bv;
      }
    }
  }
}

// Flash attention, S^T formulation, fixed-offset softmax (exp2 domain).
// Q,K: [B,H,T,D]; VT: [B,H,D,T] slot-permuted (see gemm_qkv).
// G=4: each wave owns 64 queries (4 MFMA column groups), q-block = 256.
// aK/vA fragment reads (16 b128/tile) are shared across the g-loop ->
// LDS reads and K/V refetch per score are HALF of the g=2 version.
__global__ __launch_bounds__(256) void attn(const bf16_t* __restrict__ Q,
                                            const bf16_t* __restrict__ Kg,
                                            const bf16_t* __restrict__ VT,
                                            bf16_t* __restrict__ AO) {
  __shared__ __align__(16) bf16_t Ks[64][72];  // Ks[key][d]
  __shared__ __align__(16) bf16_t Vt[64][72];  // Vt[d][key-slot]
  const int tid = threadIdx.x;
  const int lane = tid & 63;
  const int w = tid >> 6;
  const int quad = lane >> 4;
  const int l16 = lane & 15;
  // bh on x: all 8 q-blocks of one head share one XCD's L2.
  const int bh = blockIdx.x;
  const int bb = bh >> 4;
  const int h = bh & 15;
  const int q0 = blockIdx.y * 256;
  const size_t base = (size_t)bh * T_SEQ * HD;  // == bh*HD*T_SEQ for VT

  // Q as B-operand frags: lane l16 = q, holds d = c*32 + quad*8 + j.
  bf16x8 bq[4][2];
#pragma unroll
  for (int g = 0; g < 4; g++)
#pragma unroll
    for (int c = 0; c < 2; c++)
      bq[g][c] = *(const bf16x8*)(Q + base +
                                  (size_t)(q0 + w * 64 + g * 16 + l16) * HD +
                                  c * 32 + quad * 8);

  const bf16_t one = (bf16_t)1.0f;
  const bf16x8 ones = {one, one, one, one, one, one, one, one};

  f32x4 accT[4][4];
  f32x4 accS[4];  // ones-MFMA row-sum accumulator (all rows equal)
#pragma unroll
  for (int g = 0; g < 4; g++) {
    accS[g] = f32x4{0.f, 0.f, 0.f, 0.f};
#pragma unroll
    for (int dm = 0; dm < 4; dm++) accT[g][dm] = f32x4{0.f, 0.f, 0.f, 0.f};
  }

  // Staging: thread -> (row srow, cols scol..scol+15); K rows = keys,
  // V rows = d (slot-permuted key cols). Incremental pointers.
  const int srow = tid >> 2;
  const int scol = (tid & 3) * 16;
  const bf16_t* pK = Kg + base + (size_t)srow * HD + scol;
  const bf16_t* pV = VT + base + (size_t)srow * T_SEQ + scol;

  // Prefetch tile 0.
  bf16x8 kp0 = *(const bf16x8*)pK;
  bf16x8 kp1 = *(const bf16x8*)(pK + 8);
  bf16x8 vp0 = *(const bf16x8*)pV;
  bf16x8 vp1 = *(const bf16x8*)(pV + 8);
  pK += 64 * HD;
  pV += 64;

  for (int kt = 0; kt < T_SEQ; kt += 64) {
    __syncthreads();  // all waves done reading previous tile
    *(bf16x8*)&Ks[srow][scol] = kp0;
    *(bf16x8*)&Ks[srow][scol + 8] = kp1;
    *(bf16x8*)&Vt[srow][scol] = vp0;
    *(bf16x8*)&Vt[srow][scol + 8] = vp1;
    __syncthreads();

    // Prefetch next tile (flies during the MFMA block).
    kp0 = *(const bf16x8*)pK;
    kp1 = *(const bf16x8*)(pK + 8);
    vp0 = *(const bf16x8*)pV;
    vp1 = *(const bf16x8*)(pV + 8);
    pK += 64 * HD;
    pV += 64;

    // S^T = K Q^T: A-frag lane l16 = key t*16+l16, k = c*32+quad*8+j.
    bf16x8 aK[4][2];
#pragma unroll
    for (int t = 0; t < 4; t++)
#pragma unroll
      for (int c = 0; c < 2; c++)
        aK[t][c] = *(const bf16x8*)&Ks[t * 16 + l16][c * 32 + quad * 8];

    // V^T A-frags: direct b128 reads (slot order already in HBM layout).
    bf16x8 vA[4][2];
#pragma unroll
    for (int dm = 0; dm < 4; dm++)
#pragma unroll
      for (int u = 0; u < 2; u++)
        vA[dm][u] = *(const bf16x8*)&Vt[dm * 16 + l16][u * 32 + quad * 8];

#pragma unroll
    for (int g = 0; g < 4; g++) {
      f32x4 sT[4];
#pragma unroll
      for (int t = 0; t < 4; t++) {
        sT[t] = f32x4{-16.f, -16.f, -16.f, -16.f};  // softmax offset baked in
#pragma unroll
        for (int c = 0; c < 2; c++) sT[t] = MFMA16(aK[t][c], bq[g][c], sT[t]);
      }
      bf16x8 pB[2];
#pragma unroll
      for (int u = 0; u < 2; u++) {
        f32x4 p0, p1;
#pragma unroll
        for (int e = 0; e < 4; e++) {
          p0[e] = __builtin_amdgcn_exp2f(sT[u * 2][e]);
          p1[e] = __builtin_amdgcn_exp2f(sT[u * 2 + 1][e]);
        }
        bf16x8 pb;
#pragma unroll
        for (int e = 0; e < 4; e++) {
          pb[e] = (bf16_t)p0[e];
          pb[e + 4] = (bf16_t)p1[e];
        }
        pB[u] = pb;
      }
#pragma unroll
      for (int u = 0; u < 2; u++)
        accS[g] = MFMA16(ones, pB[u], accS[g]);  // key-sums per query
#pragma unroll
      for (int dm = 0; dm < 4; dm++)
#pragma unroll
        for (int u = 0; u < 2; u++)
          accT[g][dm] = MFMA16(vA[dm][u], pB[u], accT[g][dm]);
    }
  }

  // Normalize: accS[g][0] already holds the full key-sum for query l16.
#pragma unroll
  for (int g = 0; g < 4; g++) {
    float inv = 1.f / accS[g][0];
    int m = bb * T_SEQ + q0 + w * 64 + g * 16 + l16;
#pragma unroll
    for (int dm = 0; dm < 4; dm++) {
      bf16x4 ov;
#pragma unroll
      for (int r = 0; r < 4; r++) ov[r] = (bf16_t)(accT[g][dm][r] * inv);
      *(bf16x4*)(AO + (size_t)m * E_DIM + h * HD + dm * 16 + quad * 4) = ov;
    }
  }
}

extern "C" void kernel_launch(void* const* d_in, const int* in_sizes, int n_in,
                              void* d_out, int out_size, void* d_ws,
                              size_t ws_size, hipStream_t stream) {
  const float* x = (const float*)d_in[0];
  const float* Wq = (const float*)d_in[1];
  const float* bq = (const float*)d_in[2];
  const float* Wk = (const float*)d_in[3];
  const float* bk = (const float*)d_in[4];
  const float* Wv = (const float*)d_in[5];
  const float* bv = (const float*)d_in[6];
  const float* Wo = (const float*)d_in[7];
  const float* bo = (const float*)d_in[8];
  float* out = (float*)d_out;

  bf16_t* xb = (bf16_t*)d_ws;
  bf16_t* Qb = xb + ME;        // QKV contiguous: Q, K ([B,H,T,D]), V^T ([B,H,D,T])
  bf16_t* Wcat = Qb + 3 * ME;  // [3072,1024] = Wq;Wk;Wv  (also prefetch overshoot pad)
  bf16_t* Wob = Wcat + 3 * EE;
  bf16_t* AO = xb;  // alias: x dead after QKV projection

  cvt_all<<<(int)((ME + 4 * EE) / 8 / 256), 256, 0, stream>>>(
      x, Wq, Wk, Wv, Wo, xb, Wcat, Wob);

  // Q scale folds softmax scaling AND log2(e) for the exp2-domain softmax.
  const float qscale = 0.125f * 1.44269504088896f;
  gemm_qkv<<<1536, 256, 0, stream>>>(xb, Wcat, bq, bk, bv, Qb, qscale);
  attn<<<dim3(BATCH * NH, T_SEQ / 256), 256, 0, stream>>>(Qb, Qb + ME,
                                                          Qb + 2 * ME, AO);
  gemm_o<<<512, 256, 0, stream>>>(AO, Wob, bo, out);
}

// Round 11
// 274.965 us; speedup vs baseline: 1.0529x; 1.0529x over previous
//
#include <hip/hip_runtime.h>
#include <hip/hip_bf16.h>
#include <math.h>

// f32 harness I/O; bf16 MFMA internally with fp32 accumulate.
typedef __bf16 bf16_t;
typedef bf16_t bf16x4 __attribute__((ext_vector_type(4)));
typedef bf16_t bf16x8 __attribute__((ext_vector_type(8)));
typedef float f32x4 __attribute__((ext_vector_type(4)));

#define MFMA16(a, b, c) __builtin_amdgcn_mfma_f32_16x16x32_bf16(a, b, c, 0, 0, 0)
// Async global->LDS, 16B/lane. LDS dest must be wave-uniform base + lane*16.
#define GLDS16(g, s)                                                       \
  __builtin_amdgcn_global_load_lds(                                        \
      (const __attribute__((address_space(1))) void*)(g),                  \
      (__attribute__((address_space(3))) void*)(s), 16, 0, 0)

constexpr int E_DIM = 1024;
constexpr int T_SEQ = 2048;
constexpr int BATCH = 4;
constexpr int NH = 16;
constexpr int HD = 64;
constexpr int M_TOT = BATCH * T_SEQ;  // 8192
constexpr size_t ME = (size_t)M_TOT * E_DIM;  // 2^23
constexpr size_t EE = (size_t)E_DIM * E_DIM;  // 2^20

// One conversion launch: flat elems [0,ME) -> x, then 4 weight matrices.
__global__ __launch_bounds__(256) void cvt_all(
    const float* __restrict__ x, const float* __restrict__ w0,
    const float* __restrict__ w1, const float* __restrict__ w2,
    const float* __restrict__ w3, bf16_t* __restrict__ xb,
    bf16_t* __restrict__ dcat, bf16_t* __restrict__ d3) {
  size_t i = (size_t)(blockIdx.x * blockDim.x + threadIdx.x) * 8;
  const float* s;
  bf16_t* d;
  if (i < ME) {
    s = x + i;
    d = xb + i;
  } else {
    size_t rem = i - ME;
    int wsel = (int)(rem >> 20);
    size_t off = rem & (EE - 1);
    s = ((wsel == 0) ? w0 : (wsel == 1) ? w1 : (wsel == 2) ? w2 : w3) + off;
    d = ((wsel < 3) ? (dcat + (size_t)wsel * EE) : d3) + off;
  }
  float4 a = *(const float4*)s;
  float4 b = *(const float4*)(s + 4);
  bf16x8 o;
  o[0] = (bf16_t)a.x; o[1] = (bf16_t)a.y; o[2] = (bf16_t)a.z; o[3] = (bf16_t)a.w;
  o[4] = (bf16_t)b.x; o[5] = (bf16_t)b.y; o[6] = (bf16_t)b.z; o[7] = (bf16_t)b.w;
  *(bf16x8*)d = o;
}

// Fused QKV projection, 128x128 tile, BK=64 (dual [128][32] sub-buffers:
// 32 MFMAs per barrier pair instead of 16 — halves the vmcnt-drain tax).
// 1536 blocks, 2D XCD swizzle (R7). sel = n0>>10 block-uniform:
// 0->Q [B,H,T,D], 1->K [B,H,T,D], 2->V^T [B,H,D,T] slot-permuted keys
// (t = 32u+16b+4q+m -> 32u+8q+4b+m) so attn V staging is a pure copy.
__global__ __launch_bounds__(256) void gemm_qkv(
    const bf16_t* __restrict__ A, const bf16_t* __restrict__ Wcat,
    const float* __restrict__ biq, const float* __restrict__ bik,
    const float* __restrict__ biv, bf16_t* __restrict__ QKV, float qscale) {
  __shared__ __align__(16) bf16_t As[2][128][32];
  __shared__ __align__(16) bf16_t Bs[2][128][32];
  const int tid = threadIdx.x;
  const int lane = tid & 63;
  const int w = tid >> 6;
  const int quad = lane >> 4;
  const int l16 = lane & 15;
  const int wr = w >> 1, wc = w & 1;  // 2x2 wave grid, 64x64 per wave

  // Swizzle: bid -> (mb in [0,64), nb in [0,24))
  const int bid = blockIdx.x;
  const int x8 = bid & 7;
  const int s = bid >> 3;          // [0,192)
  const int nb = (x8 >> 1) * 6 + (s % 6);
  const int mb = (x8 & 1) * 32 + (s / 6);
  const int m0 = mb * 128;
  const int n0 = nb * 128;
  constexpr int K = E_DIM;

  const int srow = tid >> 2;
  const int scol = (tid & 3) * 8;
  const bf16_t* gA = A + (size_t)(m0 + srow) * K + scol;
  const bf16_t* gB = Wcat + (size_t)(n0 + srow) * K + scol;
  bf16_t* sA0 = &As[0][0][0] + tid * 8;
  bf16_t* sA1 = &As[1][0][0] + tid * 8;
  bf16_t* sB0 = &Bs[0][0][0] + tid * 8;
  bf16_t* sB1 = &Bs[1][0][0] + tid * 8;

  f32x4 acc[4][4];
#pragma unroll
  for (int i = 0; i < 4; i++)
#pragma unroll
    for (int j = 0; j < 4; j++) acc[i][j] = f32x4{0.f, 0.f, 0.f, 0.f};

  for (int k0 = 0; k0 < K; k0 += 64) {
    GLDS16(gA + k0, sA0);
    GLDS16(gA + k0 + (size_t)64 * K, sA0 + 2048);
    GLDS16(gA + k0 + 32, sA1);
    GLDS16(gA + k0 + 32 + (size_t)64 * K, sA1 + 2048);
    GLDS16(gB + k0, sB0);
    GLDS16(gB + k0 + (size_t)64 * K, sB0 + 2048);
    GLDS16(gB + k0 + 32, sB1);
    GLDS16(gB + k0 + 32 + (size_t)64 * K, sB1 + 2048);
    __syncthreads();
#pragma unroll
    for (int c2 = 0; c2 < 2; c2++) {
      bf16x8 af[4], bfr[4];
#pragma unroll
      for (int i = 0; i < 4; i++)
        af[i] = *(const bf16x8*)&As[c2][wr * 64 + i * 16 + l16][quad * 8];
#pragma unroll
      for (int j = 0; j < 4; j++)
        bfr[j] = *(const bf16x8*)&Bs[c2][wc * 64 + j * 16 + l16][quad * 8];
#pragma unroll
      for (int i = 0; i < 4; i++)
#pragma unroll
        for (int j = 0; j < 4; j++)
          acc[i][j] = MFMA16(af[i], bfr[j], acc[i][j]);
    }
    __syncthreads();
  }

  // Epilogue: block-uniform matrix select; C/D layout col=l16, row=quad*4+r.
  const int sel = n0 >> 10;
  const float* bp = (sel == 0) ? biq : (sel == 1) ? bik : biv;
  const float scale = (sel == 0) ? qscale : 1.0f;
  bf16_t* outb = QKV + (size_t)sel * ME;
#pragma unroll
  for (int j = 0; j < 4; j++) {
    int col = n0 + wc * 64 + j * 16 + l16;
    int coln = col & 1023;
    int h = coln >> 6, d = coln & 63;
    float bvl = bp[coln];
#pragma unroll
    for (int i = 0; i < 4; i++) {
      if (sel == 2) {
        // V^T [B,H,D,T], slot-permuted keys. rows quad*4+r span m=0..3 of
        // t6 = 32u+16b+4q+m -> pi(t6) = 32u+8q+4b+m; contiguous bf16x4.
        int row0 = m0 + wr * 64 + i * 16 + quad * 4;
        int bb = row0 >> 11, t = row0 & (T_SEQ - 1);
        int t6 = t & 63;
        int tp = (t & ~63) | (t6 & 32) | ((t6 & 12) << 1) |
                 (((t6 >> 4) & 1) << 2) | (t6 & 3);
        bf16x4 ov;
#pragma unroll
        for (int r = 0; r < 4; r++) ov[r] = (bf16_t)(acc[i][j][r] + bvl);
        *(bf16x4*)(outb + ((size_t)(bb * NH + h) * HD + d) * T_SEQ + tp) = ov;
      } else {
#pragma unroll
        for (int r = 0; r < 4; r++) {
          int row = m0 + wr * 64 + i * 16 + quad * 4 + r;
          int bb = row >> 11, t = row & (T_SEQ - 1);
          float v = (acc[i][j][r] + bvl) * scale;
          outb[((size_t)(bb * NH + h) * T_SEQ + t) * HD + d] = (bf16_t)v;
        }
      }
    }
  }
}

// Output projection, 128x128 tile, BK=64 dual sub-buffers, 512 blocks,
// same 2D XCD swizzle: f32 out.
__global__ __launch_bounds__(256) void gemm_o(const bf16_t* __restrict__ A,
                                              const bf16_t* __restrict__ W,
                                              const float* __restrict__ bias,
                                              float* __restrict__ outf) {
  constexpr int N = E_DIM, K = E_DIM;
  __shared__ __align__(16) bf16_t As[2][128][32];
  __shared__ __align__(16) bf16_t Bs[2][128][32];
  const int tid = threadIdx.x;
  const int lane = tid & 63;
  const int w = tid >> 6;
  const int quad = lane >> 4;
  const int l16 = lane & 15;
  const int wr = w >> 1, wc = w & 1;

  const int bid = blockIdx.x;  // [0,512)
  const int x8 = bid & 7;
  const int s = bid >> 3;  // [0,64)
  const int nb = (x8 >> 1) * 2 + (s & 1);
  const int mb = (x8 & 1) * 32 + (s >> 1);
  const int m0 = mb * 128;
  const int n0 = nb * 128;

  const int srow = tid >> 2;
  const int scol = (tid & 3) * 8;
  const bf16_t* gA = A + (size_t)(m0 + srow) * K + scol;
  const bf16_t* gB = W + (size_t)(n0 + srow) * K + scol;
  bf16_t* sA0 = &As[0][0][0] + tid * 8;
  bf16_t* sA1 = &As[1][0][0] + tid * 8;
  bf16_t* sB0 = &Bs[0][0][0] + tid * 8;
  bf16_t* sB1 = &Bs[1][0][0] + tid * 8;

  f32x4 acc[4][4];
#pragma unroll
  for (int i = 0; i < 4; i++)
#pragma unroll
    for (int j = 0; j < 4; j++) acc[i][j] = f32x4{0.f, 0.f, 0.f, 0.f};

  for (int k0 = 0; k0 < K; k0 += 64) {
    GLDS16(gA + k0, sA0);
    GLDS16(gA + k0 + (size_t)64 * K, sA0 + 2048);
    GLDS16(gA + k0 + 32, sA1);
    GLDS16(gA + k0 + 32 + (size_t)64 * K, sA1 + 2048);
    GLDS16(gB + k0, sB0);
    GLDS16(gB + k0 + (size_t)64 * K, sB0 + 2048);
    GLDS16(gB + k0 + 32, sB1);
    GLDS16(gB + k0 + 32 + (size_t)64 * K, sB1 + 2048);
    __syncthreads();
#pragma unroll
    for (int c2 = 0; c2 < 2; c2++) {
      bf16x8 af[4], bfr[4];
#pragma unroll
      for (int i = 0; i < 4; i++)
        af[i] = *(const bf16x8*)&As[c2][wr * 64 + i * 16 + l16][quad * 8];
#pragma unroll
      for (int j = 0; j < 4; j++)
        bfr[j] = *(const bf16x8*)&Bs[c2][wc * 64 + j * 16 + l16][quad * 8];
#pragma unroll
      for (int i = 0; i < 4; i++)
#pragma unroll
        for (int j = 0; j < 4; j++)
          acc[i][j] = MFMA16(af[i], bfr[j], acc[i][j]);
    }
    __syncthreads();
  }

#pragma unroll
  for (int j = 0; j < 4; j++) {
    int col = n0 + wc * 64 + j * 16 + l16;
    float bv = bias[col];
#pragma unroll
    for (int i = 0; i < 4; i++) {
#pragma unroll
      for (int r = 0; r < 4; r++) {
        int row = m0 + wr * 64 + i * 16 + quad * 4 + r;
        outf[(size_t)row * N + col] = acc[i][j][r] + bv;
      }
    }
  }
}

// Flash attention, S^T formulation, fixed-offset softmax (exp2 domain).
// Q,K: [B,H,T,D]; VT: [B,H,D,T] slot-permuted (see gemm_qkv) — V staging
// is a pure b128 tile copy. G=2 (proven best: VGPR 88, ~19.5% occupancy;
// G=4 regressed to 10.7% occupancy, R10). Incremental prefetch pointers;
// final-iteration overshoot reads allocated workspace (Wcat follows VT).
__global__ __launch_bounds__(256) void attn(const bf16_t* __restrict__ Q,
                                            const bf16_t* __restrict__ Kg,
                                            const bf16_t* __restrict__ VT,
                                            bf16_t* __restrict__ AO) {
  __shared__ __align__(16) bf16_t Ks[64][72];  // Ks[key][d]
  __shared__ __align__(16) bf16_t Vt[64][72];  // Vt[d][key-slot]
  const int tid = threadIdx.x;
  const int lane = tid & 63;
  const int w = tid >> 6;
  const int quad = lane >> 4;
  const int l16 = lane & 15;
  // bh on x: all 16 q-blocks of one head share one XCD's L2.
  const int bh = blockIdx.x;
  const int bb = bh >> 4;
  const int h = bh & 15;
  const int q0 = blockIdx.y * 128;
  const size_t base = (size_t)bh * T_SEQ * HD;  // == bh*HD*T_SEQ for VT

  // Q as B-operand frags: lane l16 = q, holds d = c*32 + quad*8 + j.
  bf16x8 bq[2][2];
#pragma unroll
  for (int g = 0; g < 2; g++)
#pragma unroll
    for (int c = 0; c < 2; c++)
      bq[g][c] = *(const bf16x8*)(Q + base +
                                  (size_t)(q0 + w * 32 + g * 16 + l16) * HD +
                                  c * 32 + quad * 8);

  const bf16_t one = (bf16_t)1.0f;
  const bf16x8 ones = {one, one, one, one, one, one, one, one};

  f32x4 accT[2][4];
  f32x4 accS[2];  // ones-MFMA row-sum accumulator (all rows equal)
#pragma unroll
  for (int g = 0; g < 2; g++) {
    accS[g] = f32x4{0.f, 0.f, 0.f, 0.f};
#pragma unroll
    for (int dm = 0; dm < 4; dm++) accT[g][dm] = f32x4{0.f, 0.f, 0.f, 0.f};
  }

  // Staging: thread -> (row srow, cols scol..scol+15); K rows = keys,
  // V rows = d (slot-permuted key cols). Incremental pointers.
  const int srow = tid >> 2;
  const int scol = (tid & 3) * 16;
  const bf16_t* pK = Kg + base + (size_t)srow * HD + scol;
  const bf16_t* pV = VT + base + (size_t)srow * T_SEQ + scol;

  // Prefetch tile 0.
  bf16x8 kp0 = *(const bf16x8*)pK;
  bf16x8 kp1 = *(const bf16x8*)(pK + 8);
  bf16x8 vp0 = *(const bf16x8*)pV;
  bf16x8 vp1 = *(const bf16x8*)(pV + 8);
  pK += 64 * HD;
  pV += 64;

  for (int kt = 0; kt < T_SEQ; kt += 64) {
    __syncthreads();  // all waves done reading previous tile
    *(bf16x8*)&Ks[srow][scol] = kp0;
    *(bf16x8*)&Ks[srow][scol + 8] = kp1;
    *(bf16x8*)&Vt[srow][scol] = vp0;
    *(bf16x8*)&Vt[srow][scol + 8] = vp1;
    __syncthreads();

    // Prefetch next tile (flies during the MFMA block).
    kp0 = *(const bf16x8*)pK;
    kp1 = *(const bf16x8*)(pK + 8);
    vp0 = *(const bf16x8*)pV;
    vp1 = *(const bf16x8*)(pV + 8);
    pK += 64 * HD;
    pV += 64;

    // S^T = K Q^T: A-frag lane l16 = key t*16+l16, k = c*32+quad*8+j.
    bf16x8 aK[4][2];
#pragma unroll
    for (int t = 0; t < 4; t++)
#pragma unroll
      for (int c = 0; c < 2; c++)
        aK[t][c] = *(const bf16x8*)&Ks[t * 16 + l16][c * 32 + quad * 8];

    // V^T A-frags: direct b128 reads (slot order already in HBM layout).
    bf16x8 vA[4][2];
#pragma unroll
    for (int dm = 0; dm < 4; dm++)
#pragma unroll
      for (int u = 0; u < 2; u++)
        vA[dm][u] = *(const bf16x8*)&Vt[dm * 16 + l16][u * 32 + quad * 8];

#pragma unroll
    for (int g = 0; g < 2; g++) {
      f32x4 sT[4];
#pragma unroll
      for (int t = 0; t < 4; t++) {
        sT[t] = f32x4{-16.f, -16.f, -16.f, -16.f};  // softmax offset baked in
#pragma unroll
        for (int c = 0; c < 2; c++) sT[t] = MFMA16(aK[t][c], bq[g][c], sT[t]);
      }
      bf16x8 pB[2];
#pragma unroll
      for (int u = 0; u < 2; u++) {
        f32x4 p0, p1;
#pragma unroll
        for (int e = 0; e < 4; e++) {
          p0[e] = __builtin_amdgcn_exp2f(sT[u * 2][e]);
          p1[e] = __builtin_amdgcn_exp2f(sT[u * 2 + 1][e]);
        }
        bf16x8 pb;
#pragma unroll
        for (int e = 0; e < 4; e++) {
          pb[e] = (bf16_t)p0[e];
          pb[e + 4] = (bf16_t)p1[e];
        }
        pB[u] = pb;
      }
#pragma unroll
      for (int u = 0; u < 2; u++)
        accS[g] = MFMA16(ones, pB[u], accS[g]);  // key-sums per query
#pragma unroll
      for (int dm = 0; dm < 4; dm++)
#pragma unroll
        for (int u = 0; u < 2; u++)
          accT[g][dm] = MFMA16(vA[dm][u], pB[u], accT[g][dm]);
    }
  }

  // Normalize: accS[g][0] already holds the full key-sum for query l16.
#pragma unroll
  for (int g = 0; g < 2; g++) {
    float inv = 1.f / accS[g][0];
    int m = bb * T_SEQ + q0 + w * 32 + g * 16 + l16;
#pragma unroll
    for (int dm = 0; dm < 4; dm++) {
      bf16x4 ov;
#pragma unroll
      for (int r = 0; r < 4; r++) ov[r] = (bf16_t)(accT[g][dm][r] * inv);
      *(bf16x4*)(AO + (size_t)m * E_DIM + h * HD + dm * 16 + quad * 4) = ov;
    }
  }
}

extern "C" void kernel_launch(void* const* d_in, const int* in_sizes, int n_in,
                              void* d_out, int out_size, void* d_ws,
                              size_t ws_size, hipStream_t stream) {
  const float* x = (const float*)d_in[0];
  const float* Wq = (const float*)d_in[1];
  const float* bq = (const float*)d_in[2];
  const float* Wk = (const float*)d_in[3];
  const float* bk = (const float*)d_in[4];
  const float* Wv = (const float*)d_in[5];
  const float* bv = (const float*)d_in[6];
  const float* Wo = (const float*)d_in[7];
  const float* bo = (const float*)d_in[8];
  float* out = (float*)d_out;

  bf16_t* xb = (bf16_t*)d_ws;
  bf16_t* Qb = xb + ME;        // QKV contiguous: Q, K ([B,H,T,D]), V^T ([B,H,D,T])
  bf16_t* Wcat = Qb + 3 * ME;  // [3072,1024] = Wq;Wk;Wv  (also prefetch overshoot pad)
  bf16_t* Wob = Wcat + 3 * EE;
  bf16_t* AO = xb;  // alias: x dead after QKV projection

  cvt_all<<<(int)((ME + 4 * EE) / 8 / 256), 256, 0, stream>>>(
      x, Wq, Wk, Wv, Wo, xb, Wcat, Wob);

  // Q scale folds softmax scaling AND log2(e) for the exp2-domain softmax.
  const float qscale = 0.125f * 1.44269504088896f;
  gemm_qkv<<<1536, 256, 0, stream>>>(xb, Wcat, bq, bk, bv, Qb, qscale);
  attn<<<dim3(BATCH * NH, T_SEQ / 128), 256, 0, stream>>>(Qb, Qb + ME,
                                                          Qb + 2 * ME, AO);
  gemm_o<<<512, 256, 0, stream>>>(AO, Wob, bo, out);
}